// Round 1
// baseline (9369.077 us; speedup 1.0000x reference)
//
#include <hip/hip_runtime.h>
#include <stdint.h>

using short8 = __attribute__((ext_vector_type(8))) short;
using f32x4  = __attribute__((ext_vector_type(4))) float;

#define DEV static __device__ __forceinline__

DEV unsigned short f2bf(float f){
  unsigned u = __builtin_bit_cast(unsigned, f);
  u = (u + 0x7FFFu + ((u >> 16) & 1u)) >> 16;
  return (unsigned short)u;
}
DEV float sigm(float x){
  float e = __builtin_amdgcn_exp2f(-1.4426950408889634f * x);
  return __builtin_amdgcn_rcpf(1.0f + e);
}
DEV float tanh_(float x){
  float e = __builtin_amdgcn_exp2f(2.885390081777927f * x); // exp(2x)
  return 1.0f - 2.0f * __builtin_amdgcn_rcpf(e + 1.0f);
}

// ---------------- aux kernels ----------------

__global__ void k_f32_to_bf16(const float* __restrict__ in, unsigned short* __restrict__ out, int n){
  int stride = gridDim.x * blockDim.x * 4;
  for (int i = (blockIdx.x * blockDim.x + threadIdx.x) * 4; i < n; i += stride){
    float4 v = *(const float4*)(in + i);
    ushort4 o4;
    o4.x = f2bf(v.x); o4.y = f2bf(v.y); o4.z = f2bf(v.z); o4.w = f2bf(v.w);
    *(ushort4*)(out + i) = o4;
  }
}

__global__ void k_add_bf16(const float* __restrict__ a, const float* __restrict__ b,
                           unsigned short* __restrict__ out, int n){
  int stride = gridDim.x * blockDim.x * 4;
  for (int i = (blockIdx.x * blockDim.x + threadIdx.x) * 4; i < n; i += stride){
    float4 va = *(const float4*)(a + i);
    float4 vb = *(const float4*)(b + i);
    ushort4 o4;
    o4.x = f2bf(va.x + vb.x); o4.y = f2bf(va.y + vb.y);
    o4.z = f2bf(va.z + vb.z); o4.w = f2bf(va.w + vb.w);
    *(ushort4*)(out + i) = o4;
  }
}

__global__ void k_add_f32(float* __restrict__ o, const float* __restrict__ b, int n){
  int stride = gridDim.x * blockDim.x * 4;
  for (int i = (blockIdx.x * blockDim.x + threadIdx.x) * 4; i < n; i += stride){
    float4 vo = *(const float4*)(o + i);
    float4 vb = *(const float4*)(b + i);
    vo.x += vb.x; vo.y += vb.y; vo.z += vb.z; vo.w += vb.w;
    *(float4*)(o + i) = vo;
  }
}

// Pack [k; r] (f32, [K, 4U] each, K split KX|U) into per-(dir,wg,wave,ktile,ntile)
// MFMA B-fragment order: idx = ((((wg*4+w)*6+kt)*4+nt)*64+lane)*8+j
// lane: col = lane&15 (within ntile, ntile == gate), kgroup = lane>>4; k = ktile*32 + kgroup*8 + j
__global__ void k_pack(const float* __restrict__ k0, const float* __restrict__ r0,
                       const float* __restrict__ k1, const float* __restrict__ r1,
                       unsigned short* __restrict__ out, int E, int KX, int U){
  int n = 2 * E;
  int stride = gridDim.x * blockDim.x;
  for (int i = blockIdx.x * blockDim.x + threadIdx.x; i < n; i += stride){
    int d = i / E, r = i % E;
    const float* Km = d ? k1 : k0;
    const float* Rm = d ? r1 : r0;
    int j    = r & 7;  int q = r >> 3;
    int lane = q & 63; q >>= 6;
    int nt   = q & 3;  q >>= 2;
    int kt   = q % 6;  q /= 6;
    int w    = q & 3;  int wg = q >> 2;
    int k    = (w*6 + kt)*32 + ((lane >> 4) << 3) + j;
    int col  = nt * U + wg*16 + (lane & 15);   // gate-major global column
    float v  = (k < KX) ? Km[(size_t)k * (4*U) + col]
                        : Rm[(size_t)(k - KX) * (4*U) + col];
    out[i] = f2bf(v);
  }
}

// ---------------- persistent recurrence kernel ----------------
// One bidirectional LSTM layer. grid = 2*WGS blocks (fwd group, bwd group).
// Each WG: 4 waves, owns 16 hidden units (64 z-columns, gate-major).
// K split across waves (6 ktiles each); B fragments preloaded in registers.
// Per step: MFMA partials -> LDS reduce -> gates/state -> h broadcast -> group flag barrier.
template<int KX, int U, int WGS>
__global__ __launch_bounds__(256, 1)
void lstm_rec(const unsigned short* __restrict__ xab,    // [64][512][KX] bf16
              const unsigned short* __restrict__ packedB,// per-dir packed [k;r]
              const float* __restrict__ bias_f,
              const float* __restrict__ bias_b,
              const int*   __restrict__ sizes,
              unsigned short* __restrict__ hbuf,         // [2 dirs][2][64][U] bf16
              unsigned int*  __restrict__ flags,         // [2 dirs][WGS*32]
              float* __restrict__ out_f,                 // [64][512][U]
              float* __restrict__ out_b)
{
  constexpr int KT  = (KX + U) / 32;   // 24
  constexpr int KTW = KT / 4;          // 6 ktiles per wave
  constexpr int T   = 512;

  const int tid  = threadIdx.x;
  const int w    = tid >> 6;
  const int lane = tid & 63;
  const int dir  = (blockIdx.x >= WGS) ? 1 : 0;
  const int wg   = dir ? (int)blockIdx.x - WGS : (int)blockIdx.x;

  const unsigned short* pB = packedB + (size_t)dir * ((size_t)WGS*4*KTW*4*512)
                                     + (size_t)((wg*4 + w)*KTW)*4*512;
  unsigned short* hb = hbuf + (size_t)dir * (2*64*U);
  unsigned int*   flg = flags + dir * (WGS*32);
  const float* bias = dir ? bias_b : bias_f;
  float* outp       = dir ? out_b : out_f;

  // preload B fragments (step-invariant) into registers: 96 VGPRs
  short8 bfr[KTW][4];
  #pragma unroll
  for (int kt = 0; kt < KTW; ++kt)
    #pragma unroll
    for (int nt = 0; nt < 4; ++nt)
      bfr[kt][nt] = *(const short8*)(pB + ((kt*4 + nt)*512) + lane*8);

  // gate-phase ownership: unit u_l (0..15), rows rb..rb+3
  const int u_l = tid & 15;
  const int rb  = (tid >> 4) * 4;
  const int ug  = wg*16 + u_l;
  float bz[4]; int sz[4];
  #pragma unroll
  for (int g = 0; g < 4; ++g) bz[g] = bias[g*U + ug];
  #pragma unroll
  for (int r = 0; r < 4; ++r) sz[r] = sizes[rb + r];
  float c[4]    = {0.f,0.f,0.f,0.f};
  float hreg[4] = {0.f,0.f,0.f,0.f};

  __shared__ float part[4][64][65];   // wave partials, padded vs bank conflicts

  const int arow = lane & 15;         // A-frag row within mtile
  const int kgrp = (lane >> 4) * 8;   // A-frag k offset within ktile

  for (int s = 0; s < T; ++s){
    const int t   = dir ? (T - 1 - s) : s;
    const int par = s & 1;

    f32x4 acc[4][4];
    #pragma unroll
    for (int mt = 0; mt < 4; ++mt)
      #pragma unroll
      for (int nt = 0; nt < 4; ++nt)
        acc[mt][nt] = (f32x4){0.f, 0.f, 0.f, 0.f};

    #pragma unroll
    for (int kt = 0; kt < KTW; ++kt){
      const int kg = (w*KTW + kt) * 32;
      #pragma unroll
      for (int mt = 0; mt < 4; ++mt){
        const int row = mt*16 + arow;   // batch row
        const unsigned short* ap;
        if (kg < KX) ap = xab + ((size_t)(row*T + t))*KX + (kg + kgrp);
        else         ap = hb + (size_t)par*64*U + (size_t)row*U + (kg - KX + kgrp);
        short8 a = *(const short8*)ap;
        #pragma unroll
        for (int nt = 0; nt < 4; ++nt)
          acc[mt][nt] = __builtin_amdgcn_mfma_f32_16x16x32_bf16(a, bfr[kt][nt], acc[mt][nt], 0, 0, 0);
      }
    }

    // D-frag: col = lane&15, row = (lane>>4)*4 + reg
    #pragma unroll
    for (int mt = 0; mt < 4; ++mt)
      #pragma unroll
      for (int nt = 0; nt < 4; ++nt)
        #pragma unroll
        for (int r2 = 0; r2 < 4; ++r2)
          part[w][mt*16 + (lane >> 4)*4 + r2][nt*16 + arow] = acc[mt][nt][r2];

    __syncthreads();

    #pragma unroll
    for (int r = 0; r < 4; ++r){
      float z0 = bz[0], z1 = bz[1], z2 = bz[2], z3 = bz[3];
      #pragma unroll
      for (int ww = 0; ww < 4; ++ww){
        z0 += part[ww][rb + r][ 0 + u_l];
        z1 += part[ww][rb + r][16 + u_l];
        z2 += part[ww][rb + r][32 + u_l];
        z3 += part[ww][rb + r][48 + u_l];
      }
      float ig = sigm(z0);
      float fg = sigm(z1);
      float gg = tanh_(z2);
      float og = sigm(z3);
      float cn = fg * c[r] + ig * gg;
      float hn = og * tanh_(cn);
      bool m  = (t < sz[r]);
      c[r] = m ? cn : c[r];
      float h = m ? hn : hreg[r];
      hreg[r] = h;
      hb[(size_t)(par ^ 1)*64*U + (size_t)(rb + r)*U + ug] = f2bf(h);
      outp[((size_t)(rb + r)*T + t)*U + ug] = h;
    }

    if (s != T - 1){
      __syncthreads();  // drains each wave's vmcnt: h stores are in L2
      if (tid == 0){
        __threadfence(); // agent release: write back shared L2 to coherence point
        __hip_atomic_store(&flg[wg*32], (unsigned)(s + 1), __ATOMIC_RELAXED, __HIP_MEMORY_SCOPE_AGENT);
      }
      if (tid < 64){
        const unsigned tgt = (unsigned)(s + 1);
        for (;;){
          unsigned v = (lane < WGS)
            ? __hip_atomic_load(&flg[lane*32], __ATOMIC_RELAXED, __HIP_MEMORY_SCOPE_AGENT)
            : tgt;
          if (__all(v >= tgt)) break;
          __builtin_amdgcn_s_sleep(1);
        }
        if (tid == 0) __threadfence(); // agent acquire: invalidate L1/L2
      }
      __syncthreads();
    }
  }
}

// ---------------- launch ----------------

extern "C" void kernel_launch(void* const* d_in, const int* in_sizes, int n_in,
                              void* d_out, int out_size, void* d_ws, size_t ws_size,
                              hipStream_t stream){
  const float* x      = (const float*)d_in[0];
  const int*   sizes  = (const int*)  d_in[1];
  const float* enc_kf = (const float*)d_in[2];
  const float* enc_rf = (const float*)d_in[3];
  const float* enc_bf = (const float*)d_in[4];
  const float* enc_kb = (const float*)d_in[5];
  const float* enc_rb = (const float*)d_in[6];
  const float* enc_bb = (const float*)d_in[7];
  const float* dec_kf = (const float*)d_in[8];
  const float* dec_rf = (const float*)d_in[9];
  const float* dec_bf = (const float*)d_in[10];
  const float* dec_kb = (const float*)d_in[11];
  const float* dec_rb = (const float*)d_in[12];
  const float* dec_bb = (const float*)d_in[13];
  float* out = (float*)d_out;
  char*  ws  = (char*)d_ws;

  const size_t o_xbf   = 0;                        // 33,554,432  x as bf16 [64][512][512]
  const size_t o_esum  = o_xbf   + 33554432ull;    // 16,777,216  enc fwd+bwd sum bf16 [64][512][256]
  const size_t o_pBe   = o_esum  + 16777216ull;    //  3,145,728  packed enc [k;r] both dirs
  const size_t o_pBd   = o_pBe   + 3145728ull;     //  6,291,456  packed dec [k;r] both dirs
  const size_t o_hfe   = o_pBd   + 6291456ull;     // 33,554,432  enc fwd h f32
  const size_t o_hbe   = o_hfe   + 33554432ull;    // 33,554,432  enc bwd h f32
  const size_t o_hbd   = o_hbe   + 33554432ull;    // 67,108,864  dec bwd h f32
  const size_t o_hbufe = o_hbd   + 67108864ull;    //    131,072  enc h exchange (2 dirs x dbuf)
  const size_t o_hbufd = o_hbufe + 131072ull;      //    262,144  dec h exchange
  const size_t o_flge  = o_hbufd + 262144ull;      //      4,096  enc flags
  const size_t o_flgd  = o_flge  + 4096ull;        //      8,192  dec flags
  const size_t total   = o_flgd  + 8192ull;        // 194,392,064 bytes
  if (ws_size < total) return;

  unsigned short* xbf   = (unsigned short*)(ws + o_xbf);
  unsigned short* esum  = (unsigned short*)(ws + o_esum);
  unsigned short* pBe   = (unsigned short*)(ws + o_pBe);
  unsigned short* pBd   = (unsigned short*)(ws + o_pBd);
  float*          hfe   = (float*)(ws + o_hfe);
  float*          hbe   = (float*)(ws + o_hbe);
  float*          hbd   = (float*)(ws + o_hbd);
  unsigned short* hbufe = (unsigned short*)(ws + o_hbufe);
  unsigned short* hbufd = (unsigned short*)(ws + o_hbufd);
  unsigned int*   flge  = (unsigned int*)(ws + o_flge);
  unsigned int*   flgd  = (unsigned int*)(ws + o_flgd);

  // zero h exchange buffers + flags (every call -> deterministic replays)
  hipMemsetAsync(ws + o_hbufe, 0, 131072ull + 262144ull + 4096ull + 8192ull, stream);

  // x -> bf16
  k_f32_to_bf16<<<2048, 256, 0, stream>>>(x, xbf, 64*512*512);

  // pack weights: enc (KX=512,U=256,WGS=16,E=786432), dec (KX=256,U=512,WGS=32,E=1572864)
  k_pack<<<2048, 256, 0, stream>>>(enc_kf, enc_rf, enc_kb, enc_rb, pBe, 786432, 512, 256);
  k_pack<<<2048, 256, 0, stream>>>(dec_kf, dec_rf, dec_kb, dec_rb, pBd, 1572864, 256, 512);

  // encoder bilstm (fwd group 16 WGs + bwd group 16 WGs)
  lstm_rec<512, 256, 16><<<32, 256, 0, stream>>>(xbf, pBe, enc_bf, enc_bb, sizes,
                                                 hbufe, flge, hfe, hbe);
  // enc_sum = bf16(hf + hb)
  k_add_bf16<<<2048, 256, 0, stream>>>(hfe, hbe, esum, 64*512*256);

  // decoder bilstm: fwd writes d_out directly, bwd to ws
  lstm_rec<256, 512, 32><<<64, 256, 0, stream>>>(esum, pBd, dec_bf, dec_bb, sizes,
                                                 hbufd, flgd, out, hbd);
  // d_out += dec bwd
  k_add_f32<<<2048, 256, 0, stream>>>(out, hbd, 64*512*512);
}